// Round 2
// baseline (1095.193 us; speedup 1.0000x reference)
//
#include <hip/hip_runtime.h>
#include <math.h>

#define NTOK 87040
#define DIM 512
#define NH 8
#define C2 0.1803368801111204f   // log2(e) / sqrt(64)

// ---------------------------------------------------------------------------
// Kernel 1: Q = query @ Wq + bq     (1 row per block)
// ---------------------------------------------------------------------------
__global__ __launch_bounds__(256)
void k_qproj(const float* __restrict__ X, const float* __restrict__ W,
             const float* __restrict__ bias, float* __restrict__ Y) {
    __shared__ float xr[DIM];
    const int r = blockIdx.x, t = threadIdx.x;
    for (int i = t; i < DIM; i += 256) xr[i] = X[(size_t)r * DIM + i];
    __syncthreads();
    #pragma unroll
    for (int rep = 0; rep < 2; ++rep) {
        const int c = t + rep * 256;
        float a = bias[c];
        #pragma unroll 4
        for (int d = 0; d < DIM; ++d) a = fmaf(xr[d], W[d * DIM + c], a);
        Y[(size_t)r * DIM + c] = a;
    }
}

// ---------------------------------------------------------------------------
// Kernel 2: qt2[r,h,d] = C2 * sum_j Q[r,h*64+j] * Wk[d, h*64+j]
//           qb2[r,h]   = C2 * sum_j Q[r,h*64+j] * bk[h*64+j]
// ---------------------------------------------------------------------------
__global__ __launch_bounds__(256)
void k_qtilde(const float* __restrict__ Q, const float* __restrict__ Wk,
              const float* __restrict__ bk, float* __restrict__ qt2,
              float* __restrict__ qb2) {
    __shared__ float qr[DIM];
    const int r = blockIdx.x, t = threadIdx.x;
    for (int i = t; i < DIM; i += 256) qr[i] = Q[(size_t)r * DIM + i];
    __syncthreads();
    if (t < NH) {
        float a = 0.f;
        for (int j = 0; j < 64; ++j) a = fmaf(qr[t * 64 + j], bk[t * 64 + j], a);
        qb2[r * NH + t] = a * C2;
    }
    for (int chunk = 0; chunk < 16; ++chunk) {
        const int c = chunk * 256 + t;      // c = h*512 + d
        const int h = c >> 9, d = c & 511;
        const float* wp = Wk + (size_t)d * DIM + h * 64;
        const float* qp = qr + h * 64;
        float a = 0.f;
        #pragma unroll 4
        for (int j = 0; j < 64; ++j) a = fmaf(qp[j], wp[j], a);
        qt2[(size_t)r * (NH * DIM) + c] = a * C2;
    }
}

// ---------------------------------------------------------------------------
// Kernel 3: attention. Block (256 thr, 4 waves) = (row, key-half).
// Wave w: head group hg=w>>1 (4 heads), level kc=(half<<1)|(w&1), 128 keys.
// No-max softmax in exp2 domain; reduce-scatter leaves head (lane>>3)&3's
// score total in each lane; raw-token weighted sums accumulated per head.
// ---------------------------------------------------------------------------
__global__ __launch_bounds__(256, 4)
void k_attn(const float* __restrict__ value, const float* __restrict__ tc_,
            const float* __restrict__ fc_, const float* __restrict__ qt2,
            const float* __restrict__ qb2, float* __restrict__ ts_part,
            float* __restrict__ l_part) {
    // XCD swizzle: keep each row's two half-blocks on one XCD (2048 % 8 == 0)
    const int bid  = ((int)blockIdx.x & 7) * 256 + ((int)blockIdx.x >> 3);
    const int r    = bid >> 1, half = bid & 1;
    const int b    = r >> 9;
    const int t    = threadIdx.x;
    const int w    = t >> 6;
    const int lane = t & 63;
    const int hg   = w >> 1;              // head group 0/1
    const int kc   = (half << 1) | (w & 1);  // level 0..3 == key chunk

    __shared__ float tsum[NH][DIM];       // 16 KB
    __shared__ float wl[2][NH];

    const float tc = tc_[r], fc = fc_[r];
    const int Wl   = 1024 >> kc;
    const int Hl   = 64 >> kc;
    const int lsi  = (kc == 0) ? 0 : (kc == 1) ? 65536 : (kc == 2) ? 81920 : 86016;
    const int tcpx = (int)rintf(tc * (float)Wl - 0.5f);
    const int fcpx = (int)rintf(fc * (float)Hl - 0.5f);

    // q-tilde: 4 heads x this lane's 8 dims
    float qt[4][8];
    const float* qtp = qt2 + (size_t)r * (NH * DIM) + (hg * 4) * DIM + lane * 8;
    #pragma unroll
    for (int h = 0; h < 4; ++h) {
        const float4 a = *(const float4*)(qtp + h * DIM);
        const float4 c = *(const float4*)(qtp + h * DIM + 4);
        qt[h][0] = a.x; qt[h][1] = a.y; qt[h][2] = a.z; qt[h][3] = a.w;
        qt[h][4] = c.x; qt[h][5] = c.y; qt[h][6] = c.z; qt[h][7] = c.w;
    }
    const int b3 = (lane >> 3) & 1, b4 = (lane >> 4) & 1;
    const int hl_own = (b4 << 1) | b3;                    // == (lane>>3)&3
    const float qb_own = qb2[r * NH + hg * 4 + hl_own];
    int src[4];
    #pragma unroll
    for (int h = 0; h < 4; ++h)
        src[h] = ((lane & 32) | (h << 3) | (lane & 7)) << 2;  // byte addr for bpermute

    float acc[4][8];
    #pragma unroll
    for (int h = 0; h < 4; ++h)
        #pragma unroll
        for (int j = 0; j < 8; ++j) acc[h][j] = 0.f;
    float lsum = 0.f;

    const float* vbase = value + (size_t)b * NTOK * DIM;

    auto loadpair = [&](int kk, float (&tok)[2][8]) {
        #pragma unroll
        for (int kb = 0; kb < 2; ++kb) {
            const int k  = kk + kb;
            const int tt = tcpx + (k & 15) - 8;
            const int ff = fcpx + (k >> 4) - 4;
            if (tt >= 0 && tt < Wl && ff >= 0 && ff < Hl) {   // wave-uniform
                const float* sp = vbase + (size_t)(lsi + ff * Wl + tt) * DIM + lane * 8;
                const float4 a = *(const float4*)sp;
                const float4 c = *(const float4*)(sp + 4);
                tok[kb][0] = a.x; tok[kb][1] = a.y; tok[kb][2] = a.z; tok[kb][3] = a.w;
                tok[kb][4] = c.x; tok[kb][5] = c.y; tok[kb][6] = c.z; tok[kb][7] = c.w;
            } else {
                #pragma unroll
                for (int j = 0; j < 8; ++j) tok[kb][j] = 0.f;
            }
        }
    };

    auto process = [&](float (&tok)[2][8]) {
        float s[2][4];
        #pragma unroll
        for (int kb = 0; kb < 2; ++kb)
            #pragma unroll
            for (int h = 0; h < 4; ++h) {
                float a = 0.f;
                #pragma unroll
                for (int j = 0; j < 8; ++j) a = fmaf(qt[h][j], tok[kb][j], a);
                s[kb][h] = a;
            }
        // within-octet butterfly (offsets 1,2,4): s[kb][h] = octet partial
        #pragma unroll
        for (int off = 1; off <= 4; off <<= 1)
            #pragma unroll
            for (int kb = 0; kb < 2; ++kb)
                #pragma unroll
                for (int h = 0; h < 4; ++h)
                    s[kb][h] += __shfl_xor(s[kb][h], off);
        #pragma unroll
        for (int kb = 0; kb < 2; ++kb) {
            // cross-octet reduce-scatter -> lane ends with head hl_own's total
            float g0 = b3 ? s[kb][0] : s[kb][1];
            float g1 = b3 ? s[kb][2] : s[kb][3];
            float k0 = (b3 ? s[kb][1] : s[kb][0]) + __shfl_xor(g0, 8);
            float k1 = (b3 ? s[kb][3] : s[kb][2]) + __shfl_xor(g1, 8);
            float g2 = b4 ? k0 : k1;
            float kk = (b4 ? k1 : k0) + __shfl_xor(g2, 16);
            kk += __shfl_xor(kk, 32);
            const float p_own = __builtin_amdgcn_exp2f(kk + qb_own);
            lsum += p_own;
            float p[4];
            #pragma unroll
            for (int h = 0; h < 4; ++h)
                p[h] = __int_as_float(
                    __builtin_amdgcn_ds_bpermute(src[h], __float_as_int(p_own)));
            #pragma unroll
            for (int h = 0; h < 4; ++h)
                #pragma unroll
                for (int j = 0; j < 8; ++j)
                    acc[h][j] = fmaf(p[h], tok[kb][j], acc[h][j]);
        }
    };

    float ta[2][8], tb[2][8];
    loadpair(0, ta);
    for (int kk = 0; kk < 128; kk += 4) {
        loadpair(kk + 2, tb);
        process(ta);
        if (kk + 4 < 128) loadpair(kk + 4, ta);
        process(tb);
    }

    // ---- merge the 4 waves into tsum / wl ----
    if ((lane & 7) == 0 && lane < 32)
        wl[w & 1][hg * 4 + (lane >> 3)] = lsum;
    if ((w & 1) == 0) {
        #pragma unroll
        for (int h = 0; h < 4; ++h)
            #pragma unroll
            for (int j = 0; j < 8; ++j)
                tsum[hg * 4 + h][lane * 8 + j] = acc[h][j];
    }
    __syncthreads();
    if ((w & 1) == 1) {
        #pragma unroll
        for (int h = 0; h < 4; ++h)
            #pragma unroll
            for (int j = 0; j < 8; ++j)
                tsum[hg * 4 + h][lane * 8 + j] += acc[h][j];
    }
    __syncthreads();

    float* dst = ts_part + ((size_t)r * 2 + half) * (NH * DIM);
    #pragma unroll
    for (int e = 0; e < 4; ++e) {
        const int i = (e * 256 + t) * 4;
        *(float4*)(dst + i) = *(const float4*)(((const float*)tsum) + i);
    }
    if (t < NH)
        l_part[((size_t)r * 2 + half) * NH + t] = wl[0][t] + wl[1][t];
}

// ---------------------------------------------------------------------------
// Kernel 4: sum halves, normalize, (tsum/l) @ Wv + bv, then @ Wo + bo.
// 1 row per block.
// ---------------------------------------------------------------------------
__global__ __launch_bounds__(256)
void k_out(const float* __restrict__ ts_part, const float* __restrict__ l_part,
           const float* __restrict__ Wv, const float* __restrict__ bv,
           const float* __restrict__ Wo, const float* __restrict__ bo,
           float* __restrict__ out) {
    __shared__ float ts[NH][DIM];   // 16 KB
    __shared__ float o1[DIM];
    __shared__ float invl[NH];
    const int r = blockIdx.x, t = threadIdx.x;
    const float* A = ts_part + (size_t)r * 2 * (NH * DIM);
    const float* B = A + NH * DIM;
    for (int i = t; i < NH * DIM; i += 256) ((float*)ts)[i] = A[i] + B[i];
    if (t < NH)
        invl[t] = 1.f / (l_part[(size_t)r * 2 * NH + t] + l_part[((size_t)r * 2 + 1) * NH + t]);
    __syncthreads();
    #pragma unroll
    for (int rep = 0; rep < 2; ++rep) {
        const int c = t + rep * 256;
        const int h = c >> 6;
        float a = 0.f;
        #pragma unroll 4
        for (int d = 0; d < DIM; ++d) a = fmaf(ts[h][d], Wv[d * DIM + c], a);
        o1[c] = fmaf(a, invl[h], bv[c]);
    }
    __syncthreads();
    #pragma unroll
    for (int rep = 0; rep < 2; ++rep) {
        const int c = t + rep * 256;
        float a = bo[c];
        #pragma unroll 4
        for (int d = 0; d < DIM; ++d) a = fmaf(o1[d], Wo[d * DIM + c], a);
        out[(size_t)r * DIM + c] = a;
    }
}

// ---------------------------------------------------------------------------
extern "C" void kernel_launch(void* const* d_in, const int* in_sizes, int n_in,
                              void* d_out, int out_size, void* d_ws, size_t ws_size,
                              hipStream_t stream) {
    const float* query = (const float*)d_in[0];
    const float* tc    = (const float*)d_in[1];
    const float* fc    = (const float*)d_in[2];
    const float* value = (const float*)d_in[3];
    const float* Wq    = (const float*)d_in[4];
    const float* bq    = (const float*)d_in[5];
    const float* Wk    = (const float*)d_in[6];
    const float* bk    = (const float*)d_in[7];
    const float* Wv    = (const float*)d_in[8];
    const float* bv    = (const float*)d_in[9];
    const float* Wo    = (const float*)d_in[10];
    const float* bo    = (const float*)d_in[11];
    float* out = (float*)d_out;

    char* ws = (char*)d_ws;
    float* Q   = (float*)(ws);                      //  2 MB
    float* QT2 = (float*)(ws + (size_t)(2  << 20)); // 16 MB
    float* QB2 = (float*)(ws + (size_t)(18 << 20)); // 32 KB
    float* TSP = (float*)(ws + (size_t)(19 << 20)); // 32 MB (2048 x 4096 f32)
    float* LP  = (float*)(ws + (size_t)(51 << 20)); // 64 KB

    hipLaunchKernelGGL(k_qproj,  dim3(1024), dim3(256), 0, stream, query, Wq, bq, Q);
    hipLaunchKernelGGL(k_qtilde, dim3(1024), dim3(256), 0, stream, Q, Wk, bk, QT2, QB2);
    hipLaunchKernelGGL(k_attn,   dim3(2048), dim3(256), 0, stream, value, tc, fc, QT2, QB2, TSP, LP);
    hipLaunchKernelGGL(k_out,    dim3(1024), dim3(256), 0, stream, TSP, LP, Wv, bv, Wo, bo, out);
}

// Round 3
// 503.577 us; speedup vs baseline: 2.1748x; 2.1748x over previous
//
#include <hip/hip_runtime.h>
#include <math.h>

#define NTOK 87040
#define DIM 512
#define NH 8
#define C2 0.1803368801111204f   // log2(e) / sqrt(64)

typedef __attribute__((ext_vector_type(8))) short short8v;
typedef __attribute__((ext_vector_type(4))) float f32x4;

// ---------------------------------------------------------------------------
// Kernel 1: Q = query @ Wq + bq     (1 row per block)   [unchanged]
// ---------------------------------------------------------------------------
__global__ __launch_bounds__(256)
void k_qproj(const float* __restrict__ X, const float* __restrict__ W,
             const float* __restrict__ bias, float* __restrict__ Y) {
    __shared__ float xr[DIM];
    const int r = blockIdx.x, t = threadIdx.x;
    for (int i = t; i < DIM; i += 256) xr[i] = X[(size_t)r * DIM + i];
    __syncthreads();
    #pragma unroll
    for (int rep = 0; rep < 2; ++rep) {
        const int c = t + rep * 256;
        float a = bias[c];
        #pragma unroll 4
        for (int d = 0; d < DIM; ++d) a = fmaf(xr[d], W[d * DIM + c], a);
        Y[(size_t)r * DIM + c] = a;
    }
}

// ---------------------------------------------------------------------------
// Kernel 2: qt2[r,h,d] = C2 * sum_j Q[r,h*64+j] * Wk[d, h*64+j]   [unchanged]
// ---------------------------------------------------------------------------
__global__ __launch_bounds__(256)
void k_qtilde(const float* __restrict__ Q, const float* __restrict__ Wk,
              const float* __restrict__ bk, float* __restrict__ qt2,
              float* __restrict__ qb2) {
    __shared__ float qr[DIM];
    const int r = blockIdx.x, t = threadIdx.x;
    for (int i = t; i < DIM; i += 256) qr[i] = Q[(size_t)r * DIM + i];
    __syncthreads();
    if (t < NH) {
        float a = 0.f;
        for (int j = 0; j < 64; ++j) a = fmaf(qr[t * 64 + j], bk[t * 64 + j], a);
        qb2[r * NH + t] = a * C2;
    }
    for (int chunk = 0; chunk < 16; ++chunk) {
        const int c = chunk * 256 + t;      // c = h*512 + d
        const int h = c >> 9, d = c & 511;
        const float* wp = Wk + (size_t)d * DIM + h * 64;
        const float* qp = qr + h * 64;
        float a = 0.f;
        #pragma unroll 4
        for (int j = 0; j < 64; ++j) a = fmaf(qp[j], wp[j], a);
        qt2[(size_t)r * (NH * DIM) + c] = a * C2;
    }
}

// ---------------------------------------------------------------------------
// Kernel 3: MFMA window attention.  1 block (4 waves) per query row.
// Tiles of 16 keys; tok staged to LDS as bf16 hi+lo (trunc+residual),
// XOR-swizzled row-major.  S-GEMM (D[h][key]) per-wave over its 128-dim
// band, partials summed in LDS; exp2 (no-max); O-GEMM (D[h][dim]) per-wave
// over its 128-dim band with P(bf16) x tok_hi(bf16).
// ---------------------------------------------------------------------------
#define LDS_TOKHI 0
#define LDS_TOKLO 16384
#define LDS_QTHI  32768
#define LDS_QTLO  40960
#define LDS_P     49152
#define LDS_PART  50176
#define LDS_QB    52224
#define LDS_TOTAL 52256

__device__ __forceinline__ unsigned bfpack(float x, float y) {
    return (__float_as_uint(x) >> 16) | (__float_as_uint(y) & 0xFFFF0000u);
}
__device__ __forceinline__ float bftrunc(float x) {
    return __uint_as_float(__float_as_uint(x) & 0xFFFF0000u);
}

__global__ __launch_bounds__(256)
void k_attn(const float* __restrict__ value, const float* __restrict__ tc_,
            const float* __restrict__ fc_, const float* __restrict__ qt2,
            const float* __restrict__ qb2, float* __restrict__ ts,
            float* __restrict__ lout) {
    extern __shared__ char lds[];
    const int r = blockIdx.x, b = r >> 9, t = threadIdx.x;
    const int w = t >> 6, lane = t & 63;
    const int m = lane & 15, q = lane >> 4;
    const int arow = lane & 7;

    const float tcf = tc_[r], fcf = fc_[r];
    const float* vb = value + (size_t)b * NTOK * DIM;

    // ---- init: qb, P zero, q-tilde pack (hi/lo, swizzled) ----
    if (t < NH) *(float*)(lds + LDS_QB + t * 4) = qb2[r * NH + t];
    *(unsigned*)(lds + LDS_P + t * 4) = 0u;      // 1 KB P buffer zeroed
    {
        const int h = t >> 5, c = t & 31;        // h 0..7, 16 dims per thread
        const float* src = qt2 + (size_t)r * 4096 + h * 512 + c * 16;
        const float4* sp = (const float4*)src;
        float4 v0 = sp[0], v1 = sp[1], v2 = sp[2], v3 = sp[3];
        uint4 hi0, hi1, lo0, lo1;
        hi0.x = bfpack(v0.x, v0.y); hi0.y = bfpack(v0.z, v0.w);
        hi0.z = bfpack(v1.x, v1.y); hi0.w = bfpack(v1.z, v1.w);
        hi1.x = bfpack(v2.x, v2.y); hi1.y = bfpack(v2.z, v2.w);
        hi1.z = bfpack(v3.x, v3.y); hi1.w = bfpack(v3.z, v3.w);
        float4 l0, l1, l2, l3;
        l0.x = v0.x - bftrunc(v0.x); l0.y = v0.y - bftrunc(v0.y);
        l0.z = v0.z - bftrunc(v0.z); l0.w = v0.w - bftrunc(v0.w);
        l1.x = v1.x - bftrunc(v1.x); l1.y = v1.y - bftrunc(v1.y);
        l1.z = v1.z - bftrunc(v1.z); l1.w = v1.w - bftrunc(v1.w);
        l2.x = v2.x - bftrunc(v2.x); l2.y = v2.y - bftrunc(v2.y);
        l2.z = v2.z - bftrunc(v2.z); l2.w = v2.w - bftrunc(v2.w);
        l3.x = v3.x - bftrunc(v3.x); l3.y = v3.y - bftrunc(v3.y);
        l3.z = v3.z - bftrunc(v3.z); l3.w = v3.w - bftrunc(v3.w);
        lo0.x = bfpack(l0.x, l0.y); lo0.y = bfpack(l0.z, l0.w);
        lo0.z = bfpack(l1.x, l1.y); lo0.w = bfpack(l1.z, l1.w);
        lo1.x = bfpack(l2.x, l2.y); lo1.y = bfpack(l2.z, l2.w);
        lo1.z = bfpack(l3.x, l3.y); lo1.w = bfpack(l3.z, l3.w);
        const int off = c * 32;                  // byte offset of dims in row
        const int sw = h << 4;
        *(uint4*)(lds + LDS_QTHI + h * 1024 + ((off) ^ sw))      = hi0;
        *(uint4*)(lds + LDS_QTHI + h * 1024 + ((off + 16) ^ sw)) = hi1;
        *(uint4*)(lds + LDS_QTLO + h * 1024 + ((off) ^ sw))      = lo0;
        *(uint4*)(lds + LDS_QTLO + h * 1024 + ((off + 16) ^ sw)) = lo1;
    }

    // stage registers + load issuer for tile kt (16 keys, this thread: key
    // k16 = t>>4, dims (t&15)*32 .. +32)
    float4 va[8];
    float msk = 1.f;
    auto issue_loads = [&](int kt) {
        const int lev = kt >> 3;
        const int Wl = 1024 >> lev, Hl = 64 >> lev;
        const int lsi = (lev == 0) ? 0 : (lev == 1) ? 65536 : (lev == 2) ? 81920 : 86016;
        const int tcpx = (int)rintf(tcf * (float)Wl - 0.5f);
        const int fcpx = (int)rintf(fcf * (float)Hl - 0.5f);
        const int k16 = t >> 4;
        const int tt = tcpx + k16 - 8;
        const int ff = fcpx + (kt & 7) - 4;
        const bool oob = (tt < 0) | (tt >= Wl) | (ff < 0) | (ff >= Hl);
        const int row = lsi + min(max(ff, 0), Hl - 1) * Wl + min(max(tt, 0), Wl - 1);
        const float4* sp = (const float4*)(vb + (size_t)row * DIM + (t & 15) * 32);
        #pragma unroll
        for (int i = 0; i < 8; ++i) va[i] = sp[i];
        msk = oob ? 0.f : 1.f;
    };
    issue_loads(0);
    __syncthreads();

    // hoist q-tilde A-fragments (constant across tiles): 4 ksteps x hi/lo
    short8v ahi[4], alo[4];
    {
        const int asw = arow << 4;
        #pragma unroll
        for (int ks = 0; ks < 4; ++ks) {
            const int doff = (w * 128 + ks * 32 + q * 8) * 2;
            ahi[ks] = *(const short8v*)(lds + LDS_QTHI + arow * 1024 + (doff ^ asw));
            alo[ks] = *(const short8v*)(lds + LDS_QTLO + arow * 1024 + (doff ^ asw));
        }
    }

    f32x4 acco[8];
    #pragma unroll
    for (int nt = 0; nt < 8; ++nt) acco[nt] = (f32x4){0.f, 0.f, 0.f, 0.f};
    float lsum = 0.f;
    float qbh = 0.f;
    if (t < 128) qbh = *(const float*)(lds + LDS_QB + (t >> 4) * 4);

    for (int kt = 0; kt < 32; ++kt) {
        // ---- pack + write tok tile (hi/lo, swizzled) ----
        {
            const int k16 = t >> 4;
            const int swz = (k16 & 7) << 4;
            const int dbase = (t & 15) * 64;     // byte offset of dims in row
            #pragma unroll
            for (int g = 0; g < 4; ++g) {
                float4 a = va[2 * g], c = va[2 * g + 1];
                a.x *= msk; a.y *= msk; a.z *= msk; a.w *= msk;
                c.x *= msk; c.y *= msk; c.z *= msk; c.w *= msk;
                uint4 hi;
                hi.x = bfpack(a.x, a.y); hi.y = bfpack(a.z, a.w);
                hi.z = bfpack(c.x, c.y); hi.w = bfpack(c.z, c.w);
                float4 la, lc;
                la.x = a.x - bftrunc(a.x); la.y = a.y - bftrunc(a.y);
                la.z = a.z - bftrunc(a.z); la.w = a.w - bftrunc(a.w);
                lc.x = c.x - bftrunc(c.x); lc.y = c.y - bftrunc(c.y);
                lc.z = c.z - bftrunc(c.z); lc.w = c.w - bftrunc(c.w);
                uint4 lo;
                lo.x = bfpack(la.x, la.y); lo.y = bfpack(la.z, la.w);
                lo.z = bfpack(lc.x, lc.y); lo.w = bfpack(lc.z, lc.w);
                const int ob = (dbase + g * 16) ^ swz;
                *(uint4*)(lds + LDS_TOKHI + k16 * 1024 + ob) = hi;
                *(uint4*)(lds + LDS_TOKLO + k16 * 1024 + ob) = lo;
            }
        }
        __syncthreads();

        // ---- S-phase: this wave's 128-dim band ----
        f32x4 dacc = (f32x4){0.f, 0.f, 0.f, 0.f};
        {
            const int bsw = (m & 7) << 4;
            #pragma unroll
            for (int ks = 0; ks < 4; ++ks) {
                const int doff = (w * 128 + ks * 32 + q * 8) * 2;
                short8v bhi = *(const short8v*)(lds + LDS_TOKHI + m * 1024 + (doff ^ bsw));
                short8v blo = *(const short8v*)(lds + LDS_TOKLO + m * 1024 + (doff ^ bsw));
                dacc = __builtin_amdgcn_mfma_f32_16x16x32_bf16(ahi[ks], bhi, dacc, 0, 0, 0);
                dacc = __builtin_amdgcn_mfma_f32_16x16x32_bf16(ahi[ks], blo, dacc, 0, 0, 0);
                dacc = __builtin_amdgcn_mfma_f32_16x16x32_bf16(alo[ks], bhi, dacc, 0, 0, 0);
            }
        }
        if (q < 2) {
            #pragma unroll
            for (int j = 0; j < 4; ++j)
                *(float*)(lds + LDS_PART + ((w * 8 + q * 4 + j) * 16 + m) * 4) = dacc[j];
        }
        __syncthreads();

        // ---- P cooperative: sum partials, exp2, pack bf16 ----
        if (t < 128) {
            const int h = t >> 4, k = t & 15;
            float s = 0.f;
            #pragma unroll
            for (int w4 = 0; w4 < 4; ++w4)
                s += *(const float*)(lds + LDS_PART + ((w4 * 8 + h) * 16 + k) * 4);
            const float p = __builtin_amdgcn_exp2f(s + qbh);
            lsum += p;
            const unsigned u = __float_as_uint(p);
            *(unsigned short*)(lds + LDS_P + (h * 32 + k) * 2) =
                (unsigned short)((u + 0x7FFFu + ((u >> 16) & 1u)) >> 16);
        }
        __syncthreads();

        // issue next tile's global loads (overlap with O-phase)
        if (kt < 31) issue_loads(kt + 1);

        // ---- O-phase: this wave's 128-dim band ----
        {
            short8v pa = *(const short8v*)(lds + LDS_P + m * 64 + q * 16);
            #pragma unroll
            for (int nt = 0; nt < 8; ++nt) {
                const int dcol = (w * 128 + nt * 16 + m) * 2;
                short8v bo_;
                #pragma unroll
                for (int i = 0; i < 8; ++i) {
                    const int key = ((q & 1) << 3) | i;
                    bo_[i] = *(const short*)(lds + LDS_TOKHI + key * 1024 + (dcol ^ (i << 4)));
                }
                acco[nt] = __builtin_amdgcn_mfma_f32_16x16x32_bf16(pa, bo_, acco[nt], 0, 0, 0);
            }
        }
        __syncthreads();
    }

    // ---- epilogue: write O (unnormalized) and l ----
    if (q < 2) {
        float* tsr = ts + (size_t)r * 4096;
        #pragma unroll
        for (int nt = 0; nt < 8; ++nt) {
            #pragma unroll
            for (int j = 0; j < 4; ++j)
                tsr[(q * 4 + j) * 512 + w * 128 + nt * 16 + m] = acco[nt][j];
        }
    }
    if (t < 128) {
        #pragma unroll
        for (int off = 1; off <= 8; off <<= 1) lsum += __shfl_xor(lsum, off);
        if ((t & 15) == 0) lout[r * NH + (t >> 4)] = lsum;
    }
}

// ---------------------------------------------------------------------------
// Kernel 4a: o1[r][h*64+c] = inv_l[r][h] * (sum_d ts[r][h*512+d] Wv[d][h*64+c]) + bv
// 64x64 tile GEMM, grid (16 row-blocks, 8 head-blocks)
// ---------------------------------------------------------------------------
__global__ __launch_bounds__(256)
void k_gemm1(const float* __restrict__ ts, const float* __restrict__ lp,
             const float* __restrict__ Wv, const float* __restrict__ bv,
             float* __restrict__ o1) {
    __shared__ float As[32][68];   // [k][row]
    __shared__ float Bs[32][64];   // [k][col]
    const int rb = blockIdx.x, h = blockIdx.y, t = threadIdx.x;
    const int tx = t & 15, ty = t >> 4;
    float acc[4][4];
    #pragma unroll
    for (int i = 0; i < 4; ++i)
        #pragma unroll
        for (int j = 0; j < 4; ++j) acc[i][j] = 0.f;

    for (int kb = 0; kb < 16; ++kb) {
        {   // stage A (64 rows x 32 k), transposed into As[k][row]
            const int row = t >> 2, kq = t & 3;
            const float* ap = ts + (size_t)(rb * 64 + row) * 4096 + h * 512 + kb * 32 + kq * 8;
            float4 a0 = ((const float4*)ap)[0], a1 = ((const float4*)ap)[1];
            As[kq * 8 + 0][row] = a0.x; As[kq * 8 + 1][row] = a0.y;
            As[kq * 8 + 2][row] = a0.z; As[kq * 8 + 3][row] = a0.w;
            As[kq * 8 + 4][row] = a1.x; As[kq * 8 + 5][row] = a1.y;
            As[kq * 8 + 6][row] = a1.z; As[kq * 8 + 7][row] = a1.w;
            // stage B (32 k x 64 cols)
            const int kr = t >> 3, cq = t & 7;
            const float* bp = Wv + (size_t)(kb * 32 + kr) * 512 + h * 64 + cq * 8;
            *(float4*)&Bs[kr][cq * 8]     = ((const float4*)bp)[0];
            *(float4*)&Bs[kr][cq * 8 + 4] = ((const float4*)bp)[1];
        }
        __syncthreads();
        #pragma unroll 8
        for (int k = 0; k < 32; ++k) {
            float4 av = *(const float4*)&As[k][ty * 4];
            float4 bw = *(const float4*)&Bs[k][tx * 4];
            acc[0][0] = fmaf(av.x, bw.x, acc[0][0]); acc[0][1] = fmaf(av.x, bw.y, acc[0][1]);
            acc[0][2] = fmaf(av.x, bw.z, acc[0][2]); acc[0][3] = fmaf(av.x, bw.w, acc[0][3]);
            acc[1][0] = fmaf(av.y, bw.x, acc[1][0]); acc[1][1] = fmaf(av.y, bw.y, acc[1][1]);
            acc[1][2] = fmaf(av.y, bw.z, acc[1][2]); acc[1][3] = fmaf(av.y, bw.w, acc[1][3]);
            acc[2][0] = fmaf(av.z, bw.x, acc[2][0]); acc[2][1] = fmaf(av.z, bw.y, acc[2][1]);
            acc[2][2] = fmaf(av.z, bw.z, acc[2][2]); acc[2][3] = fmaf(av.z, bw.w, acc[2][3]);
            acc[3][0] = fmaf(av.w, bw.x, acc[3][0]); acc[3][1] = fmaf(av.w, bw.y, acc[3][1]);
            acc[3][2] = fmaf(av.w, bw.z, acc[3][2]); acc[3][3] = fmaf(av.w, bw.w, acc[3][3]);
        }
        __syncthreads();
    }
    #pragma unroll
    for (int i = 0; i < 4; ++i) {
        const int r = rb * 64 + ty * 4 + i;
        const float inv = 1.f / lp[r * NH + h];
        #pragma unroll
        for (int j = 0; j < 4; ++j) {
            const int c = h * 64 + tx * 4 + j;
            o1[(size_t)r * 512 + c] = acc[i][j] * inv + bv[c];
        }
    }
}

// ---------------------------------------------------------------------------
// Kernel 4b: out = o1 @ Wo + bo.  Same 64x64 tiling, grid (16, 8)
// ---------------------------------------------------------------------------
__global__ __launch_bounds__(256)
void k_gemm2(const float* __restrict__ o1, const float* __restrict__ Wo,
             const float* __restrict__ bo, float* __restrict__ out) {
    __shared__ float As[32][68];
    __shared__ float Bs[32][64];
    const int rb = blockIdx.x, cb = blockIdx.y, t = threadIdx.x;
    const int tx = t & 15, ty = t >> 4;
    float acc[4][4];
    #pragma unroll
    for (int i = 0; i < 4; ++i)
        #pragma unroll
        for (int j = 0; j < 4; ++j) acc[i][j] = 0.f;

    for (int kb = 0; kb < 16; ++kb) {
        {
            const int row = t >> 2, kq = t & 3;
            const float* ap = o1 + (size_t)(rb * 64 + row) * 512 + kb * 32 + kq * 8;
            float4 a0 = ((const float4*)ap)[0], a1 = ((const float4*)ap)[1];
            As[kq * 8 + 0][row] = a0.x; As[kq * 8 + 1][row] = a0.y;
            As[kq * 8 + 2][row] = a0.z; As[kq * 8 + 3][row] = a0.w;
            As[kq * 8 + 4][row] = a1.x; As[kq * 8 + 5][row] = a1.y;
            As[kq * 8 + 6][row] = a1.z; As[kq * 8 + 7][row] = a1.w;
            const int kr = t >> 3, cq = t & 7;
            const float* bp = Wo + (size_t)(kb * 32 + kr) * 512 + cb * 64 + cq * 8;
            *(float4*)&Bs[kr][cq * 8]     = ((const float4*)bp)[0];
            *(float4*)&Bs[kr][cq * 8 + 4] = ((const float4*)bp)[1];
        }
        __syncthreads();
        #pragma unroll 8
        for (int k = 0; k < 32; ++k) {
            float4 av = *(const float4*)&As[k][ty * 4];
            float4 bw = *(const float4*)&Bs[k][tx * 4];
            acc[0][0] = fmaf(av.x, bw.x, acc[0][0]); acc[0][1] = fmaf(av.x, bw.y, acc[0][1]);
            acc[0][2] = fmaf(av.x, bw.z, acc[0][2]); acc[0][3] = fmaf(av.x, bw.w, acc[0][3]);
            acc[1][0] = fmaf(av.y, bw.x, acc[1][0]); acc[1][1] = fmaf(av.y, bw.y, acc[1][1]);
            acc[1][2] = fmaf(av.y, bw.z, acc[1][2]); acc[1][3] = fmaf(av.y, bw.w, acc[1][3]);
            acc[2][0] = fmaf(av.z, bw.x, acc[2][0]); acc[2][1] = fmaf(av.z, bw.y, acc[2][1]);
            acc[2][2] = fmaf(av.z, bw.z, acc[2][2]); acc[2][3] = fmaf(av.z, bw.w, acc[2][3]);
            acc[3][0] = fmaf(av.w, bw.x, acc[3][0]); acc[3][1] = fmaf(av.w, bw.y, acc[3][1]);
            acc[3][2] = fmaf(av.w, bw.z, acc[3][2]); acc[3][3] = fmaf(av.w, bw.w, acc[3][3]);
        }
        __syncthreads();
    }
    #pragma unroll
    for (int i = 0; i < 4; ++i) {
        const int r = rb * 64 + ty * 4 + i;
        #pragma unroll
        for (int j = 0; j < 4; ++j) {
            const int c = cb * 64 + tx * 4 + j;
            out[(size_t)r * 512 + c] = acc[i][j] + bo[c];
        }
    }
}

// ---------------------------------------------------------------------------
extern "C" void kernel_launch(void* const* d_in, const int* in_sizes, int n_in,
                              void* d_out, int out_size, void* d_ws, size_t ws_size,
                              hipStream_t stream) {
    const float* query = (const float*)d_in[0];
    const float* tc    = (const float*)d_in[1];
    const float* fc    = (const float*)d_in[2];
    const float* value = (const float*)d_in[3];
    const float* Wq    = (const float*)d_in[4];
    const float* bq    = (const float*)d_in[5];
    const float* Wk    = (const float*)d_in[6];
    const float* bk    = (const float*)d_in[7];
    const float* Wv    = (const float*)d_in[8];
    const float* bv    = (const float*)d_in[9];
    const float* Wo    = (const float*)d_in[10];
    const float* bo    = (const float*)d_in[11];
    float* out = (float*)d_out;

    char* ws = (char*)d_ws;
    float* Q   = (float*)(ws);                      //  2 MB
    float* QT2 = (float*)(ws + (size_t)(2  << 20)); // 16 MB
    float* QB2 = (float*)(ws + (size_t)(18 << 20)); // 32 KB
    float* TS  = (float*)(ws + (size_t)(19 << 20)); // 16 MB (1024 x 4096 f32)
    float* L   = (float*)(ws + (size_t)(35 << 20)); // 32 KB (1024 x 8 f32)
    float* O1  = (float*)(ws + (size_t)(36 << 20)); //  2 MB (1024 x 512 f32)

    hipLaunchKernelGGL(k_qproj,  dim3(1024), dim3(256), 0, stream, query, Wq, bq, Q);
    hipLaunchKernelGGL(k_qtilde, dim3(1024), dim3(256), 0, stream, Q, Wk, bk, QT2, QB2);
    hipLaunchKernelGGL(k_attn,   dim3(1024), dim3(256), LDS_TOTAL, stream,
                       value, tc, fc, QT2, QB2, TS, L);
    hipLaunchKernelGGL(k_gemm1,  dim3(16, 8), dim3(256), 0, stream, TS, L, Wv, bv, O1);
    hipLaunchKernelGGL(k_gemm2,  dim3(16, 8), dim3(256), 0, stream, O1, Wo, bo, out);
}

// Round 6
// 264.523 us; speedup vs baseline: 4.1403x; 1.9037x over previous
//
#include <hip/hip_runtime.h>
#include <math.h>

#define NTOK 87040
#define DIM 512
#define NH 8
#define C2 0.1803368801111204f   // log2(e) / sqrt(64)

typedef __attribute__((ext_vector_type(8))) short short8v;
typedef __attribute__((ext_vector_type(4))) float f32x4;

__device__ __forceinline__ unsigned packpair(float x, float y) {
    // bf16(x) | bf16(y)<<16  (truncating)
    return __builtin_amdgcn_perm(__float_as_uint(y), __float_as_uint(x), 0x07060302u);
}
__device__ __forceinline__ float bftrunc(float x) {
    return __uint_as_float(__float_as_uint(x) & 0xFFFF0000u);
}

// ---------------------------------------------------------------------------
// Generic 64x64-tiled GEMM + bias: out = A @ W + b.   A:[1024x512] W:[512x512]
// grid(16, 8), 256 thr.  Also used for the Q projection.
// ---------------------------------------------------------------------------
__global__ __launch_bounds__(256)
void k_gemm2(const float* __restrict__ A, const float* __restrict__ W,
             const float* __restrict__ bias, float* __restrict__ out) {
    __shared__ float As[32][68];
    __shared__ float Bs[32][68];
    const int rb = blockIdx.x, cb = blockIdx.y, t = threadIdx.x;
    const int tx = t & 15, ty = t >> 4;
    float acc[4][4];
    #pragma unroll
    for (int i = 0; i < 4; ++i)
        #pragma unroll
        for (int j = 0; j < 4; ++j) acc[i][j] = 0.f;

    for (int kb = 0; kb < 16; ++kb) {
        {
            const int row = t >> 2, kq = t & 3;
            const float* ap = A + (size_t)(rb * 64 + row) * 512 + kb * 32 + kq * 8;
            float4 a0 = ((const float4*)ap)[0], a1 = ((const float4*)ap)[1];
            As[kq * 8 + 0][row] = a0.x; As[kq * 8 + 1][row] = a0.y;
            As[kq * 8 + 2][row] = a0.z; As[kq * 8 + 3][row] = a0.w;
            As[kq * 8 + 4][row] = a1.x; As[kq * 8 + 5][row] = a1.y;
            As[kq * 8 + 6][row] = a1.z; As[kq * 8 + 7][row] = a1.w;
            const int kr = t >> 3, cq = t & 7;
            const float* bp = W + (size_t)(kb * 32 + kr) * 512 + cb * 64 + cq * 8;
            *(float4*)&Bs[kr][cq * 8]     = ((const float4*)bp)[0];
            *(float4*)&Bs[kr][cq * 8 + 4] = ((const float4*)bp)[1];
        }
        __syncthreads();
        #pragma unroll 8
        for (int k = 0; k < 32; ++k) {
            float4 av = *(const float4*)&As[k][ty * 4];
            float4 bw = *(const float4*)&Bs[k][tx * 4];
            acc[0][0] = fmaf(av.x, bw.x, acc[0][0]); acc[0][1] = fmaf(av.x, bw.y, acc[0][1]);
            acc[0][2] = fmaf(av.x, bw.z, acc[0][2]); acc[0][3] = fmaf(av.x, bw.w, acc[0][3]);
            acc[1][0] = fmaf(av.y, bw.x, acc[1][0]); acc[1][1] = fmaf(av.y, bw.y, acc[1][1]);
            acc[1][2] = fmaf(av.y, bw.z, acc[1][2]); acc[1][3] = fmaf(av.y, bw.w, acc[1][3]);
            acc[2][0] = fmaf(av.z, bw.x, acc[2][0]); acc[2][1] = fmaf(av.z, bw.y, acc[2][1]);
            acc[2][2] = fmaf(av.z, bw.z, acc[2][2]); acc[2][3] = fmaf(av.z, bw.w, acc[2][3]);
            acc[3][0] = fmaf(av.w, bw.x, acc[3][0]); acc[3][1] = fmaf(av.w, bw.y, acc[3][1]);
            acc[3][2] = fmaf(av.w, bw.z, acc[3][2]); acc[3][3] = fmaf(av.w, bw.w, acc[3][3]);
        }
        __syncthreads();
    }
    #pragma unroll
    for (int i = 0; i < 4; ++i) {
        const int r = rb * 64 + ty * 4 + i;
        #pragma unroll
        for (int j = 0; j < 4; ++j) {
            const int c = cb * 64 + tx * 4 + j;
            out[(size_t)r * 512 + c] = acc[i][j] + bias[c];
        }
    }
}

// ---------------------------------------------------------------------------
// k_qtilde: 8 per-head GEMMs: qt2[r, h*512+d] = C2 * sum_j Q[r,h*64+j]*Wk[d,h*64+j]
// grid(16 rb, 8 db, 8 h), 64x64 tile, K=64.
// ---------------------------------------------------------------------------
__global__ __launch_bounds__(256)
void k_qtilde(const float* __restrict__ Q, const float* __restrict__ Wk,
              float* __restrict__ qt2) {
    __shared__ float AsT[64][68];   // [j][row]
    __shared__ float Bs[64][68];    // [j][d]
    const int rb = blockIdx.x, db = blockIdx.y, h = blockIdx.z, t = threadIdx.x;
    {
        const int row = t >> 2, j0 = (t & 3) * 16;
        const float* ap = Q + (size_t)(rb * 64 + row) * 512 + h * 64 + j0;
        #pragma unroll
        for (int a = 0; a < 4; ++a) {
            float4 v = ((const float4*)ap)[a];
            AsT[j0 + a * 4 + 0][row] = v.x; AsT[j0 + a * 4 + 1][row] = v.y;
            AsT[j0 + a * 4 + 2][row] = v.z; AsT[j0 + a * 4 + 3][row] = v.w;
        }
        const int d = t >> 2;
        const float* bp = Wk + (size_t)(db * 64 + d) * 512 + h * 64 + j0;
        #pragma unroll
        for (int a = 0; a < 4; ++a) {
            float4 v = ((const float4*)bp)[a];
            Bs[j0 + a * 4 + 0][d] = v.x; Bs[j0 + a * 4 + 1][d] = v.y;
            Bs[j0 + a * 4 + 2][d] = v.z; Bs[j0 + a * 4 + 3][d] = v.w;
        }
    }
    __syncthreads();
    const int tx = t & 15, ty = t >> 4;
    float acc[4][4];
    #pragma unroll
    for (int i = 0; i < 4; ++i)
        #pragma unroll
        for (int j = 0; j < 4; ++j) acc[i][j] = 0.f;
    #pragma unroll 8
    for (int k = 0; k < 64; ++k) {
        float4 av = *(const float4*)&AsT[k][ty * 4];
        float4 bw = *(const float4*)&Bs[k][tx * 4];
        acc[0][0] = fmaf(av.x, bw.x, acc[0][0]); acc[0][1] = fmaf(av.x, bw.y, acc[0][1]);
        acc[0][2] = fmaf(av.x, bw.z, acc[0][2]); acc[0][3] = fmaf(av.x, bw.w, acc[0][3]);
        acc[1][0] = fmaf(av.y, bw.x, acc[1][0]); acc[1][1] = fmaf(av.y, bw.y, acc[1][1]);
        acc[1][2] = fmaf(av.y, bw.z, acc[1][2]); acc[1][3] = fmaf(av.y, bw.w, acc[1][3]);
        acc[2][0] = fmaf(av.z, bw.x, acc[2][0]); acc[2][1] = fmaf(av.z, bw.y, acc[2][1]);
        acc[2][2] = fmaf(av.z, bw.z, acc[2][2]); acc[2][3] = fmaf(av.z, bw.w, acc[2][3]);
        acc[3][0] = fmaf(av.w, bw.x, acc[3][0]); acc[3][1] = fmaf(av.w, bw.y, acc[3][1]);
        acc[3][2] = fmaf(av.w, bw.z, acc[3][2]); acc[3][3] = fmaf(av.w, bw.w, acc[3][3]);
    }
    #pragma unroll
    for (int i = 0; i < 4; ++i) {
        const int r = rb * 64 + ty * 4 + i;
        #pragma unroll
        for (int j = 0; j < 4; ++j)
            qt2[(size_t)r * 4096 + h * 512 + db * 64 + tx * 4 + j] = acc[i][j] * C2;
    }
}

// ---------------------------------------------------------------------------
// k_qb: qb2[r,h] = C2 * sum_j Q[r,h*64+j]*bk[h*64+j].  grid(32) x 256.
// ---------------------------------------------------------------------------
__global__ __launch_bounds__(256)
void k_qb(const float* __restrict__ Q, const float* __restrict__ bk,
          float* __restrict__ qb2) {
    const int task = blockIdx.x * 256 + threadIdx.x;   // = r*8 + h
    const int r = task >> 3, h = task & 7;
    float a = 0.f;
    #pragma unroll 8
    for (int j = 0; j < 64; ++j)
        a = fmaf(Q[(size_t)r * 512 + h * 64 + j], bk[h * 64 + j], a);
    qb2[task] = a * C2;
}

// ---------------------------------------------------------------------------
// Kernel 3: MFMA window attention, 32-key tiles, scalar-u16 O-phase.
// Token LDS layout (per plane): addr(key, dim) = key*1040 + (dim*2 ^ ((key&7)<<4))
//   stride 1040 = 16-byte multiple (b128 aligned), 260 dwords == 4 mod 32
//   (consecutive keys shift banks by 4).  O-phase k-slot map: kappa(q,e)=4e+q
//   so per-instruction keys are 1 apart -> conflict-free scalar reads.
// ---------------------------------------------------------------------------
#define TSTRIDE 1040
#define TOKHI 0
#define TOKLO 33280   // 32*1040
#define PARTB 66560   // 4 KB: [w][key][head] f32
#define PLDSB 70656   // 1 KB: [16 heads][32 key-slots] bf16 (sigma-permuted)
#define LDSZ  71680

__device__ __forceinline__ int tok_addr(int key, int dimbyte) {
    return key * TSTRIDE + (dimbyte ^ ((key & 7) << 4));
}

__global__ __launch_bounds__(256, 2)
void k_attn(const float* __restrict__ value, const float* __restrict__ tc_,
            const float* __restrict__ fc_, const float* __restrict__ qt2,
            const float* __restrict__ qb2, float* __restrict__ ts,
            float* __restrict__ lout) {
    __shared__ char smem[LDSZ];
    const int r = blockIdx.x, b = r >> 9, t = threadIdx.x;
    const int w = t >> 6, lane = t & 63;
    const int m = lane & 15, q = lane >> 4;

    const float tcf = tc_[r], fcf = fc_[r];
    const float* vb = value + (size_t)b * NTOK * DIM;

    *(float*)(smem + PLDSB + t * 4) = 0.f;   // zero P (heads 8..15 stay 0)

    // ---- A-frags (q-tilde, hi/lo): head lane&7, wave's 128-dim band ----
    short8v ahi[4], alo[4];
    #pragma unroll
    for (int ks = 0; ks < 4; ++ks) {
        const float* qp = qt2 + (size_t)r * 4096 + (lane & 7) * 512 + w * 128 + ks * 32 + q * 8;
        float4 x = ((const float4*)qp)[0], y = ((const float4*)qp)[1];
        union { unsigned u[4]; short8v s; } H, L;
        H.u[0] = packpair(x.x, x.y); H.u[1] = packpair(x.z, x.w);
        H.u[2] = packpair(y.x, y.y); H.u[3] = packpair(y.z, y.w);
        L.u[0] = packpair(x.x - bftrunc(x.x), x.y - bftrunc(x.y));
        L.u[1] = packpair(x.z - bftrunc(x.z), x.w - bftrunc(x.w));
        L.u[2] = packpair(y.x - bftrunc(y.x), y.y - bftrunc(y.y));
        L.u[3] = packpair(y.z - bftrunc(y.z), y.w - bftrunc(y.w));
        ahi[ks] = H.s; alo[ks] = L.s;
    }
    const float qbh = qb2[r * NH + (t & 7)];
    const float eqb = __builtin_amdgcn_exp2f(qbh);

    // staging identity: key kk = t>>3 (0..31), dim-octet dh = t&7
    const int kk = t >> 3, dh = t & 7;

    float4 va[16];
    auto issue_loads = [&](int kt) {
        const int lev = kt >> 2;
        const int Wl = 1024 >> lev, Hl = 64 >> lev;
        const int lsi = (lev == 0) ? 0 : (lev == 1) ? 65536 : (lev == 2) ? 81920 : 86016;
        const int tcpx = (int)rintf(tcf * (float)Wl - 0.5f);
        const int fcpx = (int)rintf(fcf * (float)Hl - 0.5f);
        const int kl = (kt & 3) * 32 + kk;
        const int tt = tcpx + (kl & 15) - 8;
        const int ff = fcpx + (kl >> 4) - 4;
        const int row = lsi + min(max(ff, 0), Hl - 1) * Wl + min(max(tt, 0), Wl - 1);
        const float* sp = vb + (size_t)row * DIM + dh * 8;
        #pragma unroll
        for (int g = 0; g < 8; ++g) {
            va[2 * g]     = *(const float4*)(sp + g * 64);
            va[2 * g + 1] = *(const float4*)(sp + g * 64 + 4);
        }
    };
    issue_loads(0);

    f32x4 acco[8];
    #pragma unroll
    for (int nt = 0; nt < 8; ++nt) acco[nt] = (f32x4){0.f, 0.f, 0.f, 0.f};
    float lsum = 0.f;

    for (int kt = 0; kt < 16; ++kt) {
        // ---- pack + write tok tile: quad g = dims [g*64+dh*8, +8) ----
        {
            #pragma unroll
            for (int g = 0; g < 8; ++g) {
                float4 v0 = va[2 * g], v1 = va[2 * g + 1];
                uint4 H, L;
                H.x = packpair(v0.x, v0.y); H.y = packpair(v0.z, v0.w);
                H.z = packpair(v1.x, v1.y); H.w = packpair(v1.z, v1.w);
                L.x = packpair(v0.x - bftrunc(v0.x), v0.y - bftrunc(v0.y));
                L.y = packpair(v0.z - bftrunc(v0.z), v0.w - bftrunc(v0.w));
                L.z = packpair(v1.x - bftrunc(v1.x), v1.y - bftrunc(v1.y));
                L.w = packpair(v1.z - bftrunc(v1.z), v1.w - bftrunc(v1.w));
                const int a = tok_addr(kk, g * 128 + dh * 16);
                *(uint4*)(smem + TOKHI + a) = H;
                *(uint4*)(smem + TOKLO + a) = L;
            }
        }
        if (kt < 15) issue_loads(kt + 1);
        __syncthreads();

        // ---- S-phase: D[h][key] over this wave's 128-dim band ----
        f32x4 dacc[2];
        dacc[0] = (f32x4){0.f, 0.f, 0.f, 0.f};
        dacc[1] = (f32x4){0.f, 0.f, 0.f, 0.f};
        #pragma unroll
        for (int ks = 0; ks < 4; ++ks) {
            const int dby = w * 256 + ks * 64 + q * 16;   // dims (ks*32+q*8)*2
            #pragma unroll
            for (int ko = 0; ko < 2; ++ko) {
                const int key = m + 16 * ko;
                const int a = tok_addr(key, dby);
                short8v bhi = *(const short8v*)(smem + TOKHI + a);
                short8v blo = *(const short8v*)(smem + TOKLO + a);
                dacc[ko] = __builtin_amdgcn_mfma_f32_16x16x32_bf16(ahi[ks], bhi, dacc[ko], 0, 0, 0);
                dacc[ko] = __builtin_amdgcn_mfma_f32_16x16x32_bf16(ahi[ks], blo, dacc[ko], 0, 0, 0);
                dacc[ko] = __builtin_amdgcn_mfma_f32_16x16x32_bf16(alo[ks], bhi, dacc[ko], 0, 0, 0);
            }
        }
        if (q < 2) {
            *(f32x4*)(smem + PARTB + w * 1024 + m * 32 + q * 16) = dacc[0];
            *(f32x4*)(smem + PARTB + w * 1024 + (m + 16) * 32 + q * 16) = dacc[1];
        }
        __syncthreads();

        // ---- P-phase: thread = (key kk, head dh) ----
        {
            float s = 0.f;
            #pragma unroll
            for (int w4 = 0; w4 < 4; ++w4)
                s += *(const float*)(smem + PARTB + w4 * 1024 + kk * 32 + dh * 4);
            const int lev = kt >> 2;
            const int Wl = 1024 >> lev, Hl = 64 >> lev;
            const int tcpx = (int)rintf(tcf * (float)Wl - 0.5f);
            const int fcpx = (int)rintf(fcf * (float)Hl - 0.5f);
            const int kl = (kt & 3) * 32 + kk;
            const int tt = tcpx + (kl & 15) - 8;
            const int ff = fcpx + (kl >> 4) - 4;
            const bool oob = (tt < 0) | (tt >= Wl) | (ff < 0) | (ff >= Hl);
            const float p = __builtin_amdgcn_exp2f(s + qbh);
            lsum += oob ? eqb : p;
            unsigned short pb = 0;
            if (!oob) {
                const unsigned u = __float_as_uint(p);
                pb = (unsigned short)((u + 0x7FFFu + ((u >> 16) & 1u)) >> 16);
            }
            // sigma layout: key kk -> byte (kk&3)*16 + (kk>>2)*2  (slot kappa(q,e)=4e+q)
            *(unsigned short*)(smem + PLDSB + dh * 64 + (kk & 3) * 16 + (kk >> 2) * 2) = pb;
        }
        __syncthreads();

        // ---- O-phase: acc[head][dim] over wave's 128-dim band ----
        {
            short8v pa = *(const short8v*)(smem + PLDSB + m * 64 + q * 16);
            #pragma unroll
            for (int nt = 0; nt < 8; ++nt) {
                const int dimbyte = w * 256 + nt * 32 + m * 2;
                union { unsigned short s[8]; short8v v; } bo;
                #pragma unroll
                for (int e = 0; e < 8; ++e) {
                    const int key = 4 * e + q;   // kappa(q,e)
                    bo.s[e] = *(const unsigned short*)(smem + TOKHI + tok_addr(key, dimbyte));
                }
                acco[nt] = __builtin_amdgcn_mfma_f32_16x16x32_bf16(pa, bo.v, acco[nt], 0, 0, 0);
            }
        }
        __syncthreads();
    }

    // ---- epilogue ----
    if (q < 2) {
        float* tsr = ts + (size_t)r * 4096 + (q * 4) * 512 + w * 128 + m;
        #pragma unroll
        for (int nt = 0; nt < 8; ++nt)
            #pragma unroll
            for (int jj = 0; jj < 4; ++jj)
                tsr[jj * 512 + nt * 16] = acco[nt][jj];
    }
    lsum += __shfl_xor(lsum, 8);
    lsum += __shfl_xor(lsum, 16);
    lsum += __shfl_xor(lsum, 32);
    if (lane < 8) *(float*)(smem + PARTB + (w * 8 + lane) * 4) = lsum;
    __syncthreads();
    if (t < 8) {
        float a = 0.f;
        #pragma unroll
        for (int w4 = 0; w4 < 4; ++w4)
            a += *(const float*)(smem + PARTB + (w4 * 8 + t) * 4);
        lout[r * NH + t] = a;
    }
}

// ---------------------------------------------------------------------------
// Kernel 4a: o1 = (ts/l) @ Wv + bv   (per-head blocks), grid(16, 8)
// ---------------------------------------------------------------------------
__global__ __launch_bounds__(256)
void k_gemm1(const float* __restrict__ ts, const float* __restrict__ lp,
             const float* __restrict__ Wv, const float* __restrict__ bv,
             float* __restrict__ o1) {
    __shared__ float As[32][68];
    __shared__ float Bs[32][68];
    const int rb = blockIdx.x, h = blockIdx.y, t = threadIdx.x;
    const int tx = t & 15, ty = t >> 4;
    float acc[4][4];
    #pragma unroll
    for (int i = 0; i < 4; ++i)
        #pragma unroll
        for (int j = 0; j < 4; ++j) acc[i][j] = 0.f;

    for (int kb = 0; kb < 16; ++kb) {
        {
            const int row = t >> 2, kq = t & 3;
            const float* ap = ts + (size_t)(rb * 64 + row) * 4096 + h * 512 + kb * 32 + kq * 8;
            float4 a0 = ((const float4*)ap)[0], a1 = ((const float4*)ap)[1];
            As[kq * 8 + 0][row] = a0.x; As[kq * 8 + 1][row] = a0.y;
            As[kq * 8 + 2][row] = a0.z; As[kq * 8 + 3][row] = a0.w;
            As[kq * 8 + 4][row] = a1.x; As[kq * 8 + 5][row] = a1.y;
            As[kq * 8 + 6][row] = a1.z; As[kq * 8 + 7][row] = a1.w;
            const int kr = t >> 3, cq = t & 7;
            const float* bp = Wv + (size_t)(kb * 32 + kr) * 512 + h * 64 + cq * 8;
            *(float4*)&Bs[kr][cq * 8]     = ((const float4*)bp)[0];
            *(float4*)&Bs[kr][cq * 8 + 4] = ((const float4*)bp)[1];
        }
        __syncthreads();
        #pragma unroll 8
        for (int k = 0; k < 32; ++k) {
            float4 av = *(const float4*)&As[k][ty * 4];
            float4 bw = *(const float4*)&Bs[k][tx * 4];
            acc[0][0] = fmaf(av.x, bw.x, acc[0][0]); acc[0][1] = fmaf(av.x, bw.y, acc[0][1]);
            acc[0][2] = fmaf(av.x, bw.z, acc[0][2]); acc[0][3] = fmaf(av.x, bw.w, acc[0][3]);
            acc[1][0] = fmaf(av.y, bw.x, acc[1][0]); acc[1][1] = fmaf(av.y, bw.y, acc[1][1]);
            acc[1][2] = fmaf(av.y, bw.z, acc[1][2]); acc[1][3] = fmaf(av.y, bw.w, acc[1][3]);
            acc[2][0] = fmaf(av.z, bw.x, acc[2][0]); acc[2][1] = fmaf(av.z, bw.y, acc[2][1]);
            acc[2][2] = fmaf(av.z, bw.z, acc[2][2]); acc[2][3] = fmaf(av.z, bw.w, acc[2][3]);
            acc[3][0] = fmaf(av.w, bw.x, acc[3][0]); acc[3][1] = fmaf(av.w, bw.y, acc[3][1]);
            acc[3][2] = fmaf(av.w, bw.z, acc[3][2]); acc[3][3] = fmaf(av.w, bw.w, acc[3][3]);
        }
        __syncthreads();
    }
    #pragma unroll
    for (int i = 0; i < 4; ++i) {
        const int r = rb * 64 + ty * 4 + i;
        const float inv = 1.f / lp[r * NH + h];
        #pragma unroll
        for (int j = 0; j < 4; ++j) {
            const int c = h * 64 + tx * 4 + j;
            o1[(size_t)r * 512 + c] = acc[i][j] * inv + bv[c];
        }
    }
}

// ---------------------------------------------------------------------------
extern "C" void kernel_launch(void* const* d_in, const int* in_sizes, int n_in,
                              void* d_out, int out_size, void* d_ws, size_t ws_size,
                              hipStream_t stream) {
    const float* query = (const float*)d_in[0];
    const float* tc    = (const float*)d_in[1];
    const float* fc    = (const float*)d_in[2];
    const float* value = (const float*)d_in[3];
    const float* Wq    = (const float*)d_in[4];
    const float* bq    = (const float*)d_in[5];
    const float* Wk    = (const float*)d_in[6];
    const float* bk    = (const float*)d_in[7];
    const float* Wv    = (const float*)d_in[8];
    const float* bv    = (const float*)d_in[9];
    const float* Wo    = (const float*)d_in[10];
    const float* bo    = (const float*)d_in[11];
    float* out = (float*)d_out;

    char* ws = (char*)d_ws;
    float* Q   = (float*)(ws);                      //  2 MB
    float* QT2 = (float*)(ws + (size_t)(2  << 20)); // 16 MB
    float* QB2 = (float*)(ws + (size_t)(18 << 20)); // 32 KB
    float* TS  = (float*)(ws + (size_t)(19 << 20)); // 16 MB
    float* L   = (float*)(ws + (size_t)(35 << 20)); // 32 KB
    float* O1  = (float*)(ws + (size_t)(36 << 20)); //  2 MB

    hipLaunchKernelGGL(k_gemm2,  dim3(16, 8),    dim3(256), 0, stream, query, Wq, bq, Q);
    hipLaunchKernelGGL(k_qtilde, dim3(16, 8, 8), dim3(256), 0, stream, Q, Wk, QT2);
    hipLaunchKernelGGL(k_qb,     dim3(32),       dim3(256), 0, stream, Q, bk, QB2);
    hipLaunchKernelGGL(k_attn,   dim3(1024),     dim3(256), 0, stream,
                       value, tc, fc, QT2, QB2, TS, L);
    hipLaunchKernelGGL(k_gemm1,  dim3(16, 8),    dim3(256), 0, stream, TS, L, Wv, bv, O1);
    hipLaunchKernelGGL(k_gemm2,  dim3(16, 8),    dim3(256), 0, stream, O1, Wo, bo, out);
}